// Round 11
// baseline (291.384 us; speedup 1.0000x reference)
//
#include <hip/hip_runtime.h>

#define S_LEN 2048

typedef __attribute__((ext_vector_type(8))) short bf16x8;
typedef __attribute__((ext_vector_type(4))) float f32x4;
typedef __attribute__((ext_vector_type(4))) unsigned int u32x4;
typedef unsigned long long u64;
typedef unsigned int u32;
typedef unsigned short u16;

#define MFMA16 __builtin_amdgcn_mfma_f32_16x16x32_bf16

// single-instruction pack: a -> low16, b -> high16 (RNE)
__device__ __forceinline__ u32 cvtpk(float a, float b) {
  u32 r;
  asm("v_cvt_pk_bf16_f32 %0, %1, %2" : "=v"(r) : "v"(a), "v"(b));
  return r;
}
// raw hardware 2^x (avoid OCML wrapper ops around v_exp_f32)
__device__ __forceinline__ float exp2hw(float x) {
  float r;
  asm("v_exp_f32 %0, %1" : "=v"(r) : "v"(x));
  return r;
}

// 64x64 bf16 tile, 128B rows, 8 x 16B blocks/row, block swizzled by xor(row&7).
__device__ __forceinline__ u64* qkaddr(u16* dst, int row, int c4) {
  const int cb = c4 >> 1;
  return (u64*)((char*)dst + ((((row << 3) + (cb ^ (row & 7))) << 4) + ((c4 & 1) << 3)));
}
__device__ __forceinline__ bf16x8 ldfrag(const u16* base, int row, int blk) {
  const char* p = (const char*)base + (((row << 3) + (blk ^ (row & 7))) << 4);
  return *(const bf16x8*)p;
}

// async global->LDS, 16B per lane; LDS dst = wave-uniform base + lane*16.
__device__ __forceinline__ void gload16(const u16* g, u16* l) {
  __builtin_amdgcn_global_load_lds((const __attribute__((address_space(1))) void*)g,
                                   (__attribute__((address_space(3))) void*)l, 16, 0, 0);
}

// ---------------------------------------------------------------------------
// Pre-pass: one-time conversions into workspace (unchanged since R2).
// ---------------------------------------------------------------------------
__global__ __launch_bounds__(256) void prep_kernel(
    const float* __restrict__ gk, const float* __restrict__ gv,
    const int* __restrict__ gmask,
    u16* __restrict__ wsK, u16* __restrict__ wsV,
    u16* __restrict__ wsM, float* __restrict__ wsVs) {
  __shared__ float tile[64 * 65];   // V^T staged: tile[d*65 + k] (65-stride: bank-free)
  __shared__ float sred[2][256];    // Vsum partials
  const int bid = blockIdx.x, t = threadIdx.x;
  if (bid < 2048) {
    const int bh = bid >> 5, kt = bid & 31;
    const float* kg = gk + ((size_t)bh << 17) + ((size_t)kt << 12);
    const float* vg = gv + ((size_t)bh << 17) + ((size_t)kt << 12);
    u16* outK = wsK + ((size_t)bid << 12);
    u16* outV = wsV + ((size_t)bid << 12);
    const int r0 = t >> 4, c4 = t & 15;
#pragma unroll
    for (int i = 0; i < 4; ++i) {
      const int row = r0 + (i << 4);  // k index
      const float4 f = *(const float4*)(vg + (row << 6) + (c4 << 2));
      float* p = tile + row;
      p[((c4 << 2) + 0) * 65] = f.x;
      p[((c4 << 2) + 1) * 65] = f.y;
      p[((c4 << 2) + 2) * 65] = f.z;
      p[((c4 << 2) + 3) * 65] = f.w;
    }
#pragma unroll
    for (int i = 0; i < 2; ++i) {
      const int n = t + (i << 8);
      const int row = n >> 3, cb = (n & 7) ^ (row & 7);
      const float4 A = *(const float4*)(kg + (row << 6) + (cb << 3));
      const float4 B = *(const float4*)(kg + (row << 6) + (cb << 3) + 4);
      u32x4 w;
      w.x = cvtpk(A.x, A.y); w.y = cvtpk(A.z, A.w);
      w.z = cvtpk(B.x, B.y); w.w = cvtpk(B.z, B.w);
      *(u32x4*)(outK + ((size_t)n << 3)) = w;
    }
    __syncthreads();
#pragma unroll
    for (int i = 0; i < 2; ++i) {
      const int n = t + (i << 8);
      const int d = n >> 3, cb = (n & 7) ^ (d & 7);
      const float* src = tile + d * 65 + (cb << 3);
      float e[8], s = 0.f;
#pragma unroll
      for (int j = 0; j < 8; ++j) { e[j] = src[j]; s += e[j]; }
      sred[i][t] = s;
      u32x4 w;
      w.x = cvtpk(e[0], e[1]); w.y = cvtpk(e[2], e[3]);
      w.z = cvtpk(e[4], e[5]); w.w = cvtpk(e[6], e[7]);
      *(u32x4*)(outV + ((size_t)n << 3)) = w;
    }
    __syncthreads();
    if (t < 64) {
      const float* s8 = (t < 32) ? &sred[0][t << 3] : &sred[1][(t - 32) << 3];
      const float s = ((s8[0] + s8[1]) + (s8[2] + s8[3])) +
                      ((s8[4] + s8[5]) + (s8[6] + s8[7]));
      atomicAdd(&wsVs[(bh << 6) + t], s);
    }
  } else {
    const size_t base = ((size_t)(bid - 2048) << 12) + ((size_t)t << 4);
    int4 m[4];
#pragma unroll
    for (int i = 0; i < 4; ++i) m[i] = *(const int4*)(gmask + base + (i << 2));
    u32x4 w0, w1;
    w0.x = (m[0].x ? 0xFFFFu : 0u) | (m[0].y ? 0xFFFF0000u : 0u);
    w0.y = (m[0].z ? 0xFFFFu : 0u) | (m[0].w ? 0xFFFF0000u : 0u);
    w0.z = (m[1].x ? 0xFFFFu : 0u) | (m[1].y ? 0xFFFF0000u : 0u);
    w0.w = (m[1].z ? 0xFFFFu : 0u) | (m[1].w ? 0xFFFF0000u : 0u);
    w1.x = (m[2].x ? 0xFFFFu : 0u) | (m[2].y ? 0xFFFF0000u : 0u);
    w1.y = (m[2].z ? 0xFFFFu : 0u) | (m[2].w ? 0xFFFF0000u : 0u);
    w1.z = (m[3].x ? 0xFFFFu : 0u) | (m[3].y ? 0xFFFF0000u : 0u);
    w1.w = (m[3].z ? 0xFFFFu : 0u) | (m[3].w ? 0xFFFF0000u : 0u);
    *(u32x4*)(wsM + base) = w0;
    *(u32x4*)(wsM + base + 8) = w1;
  }
}

// ---------------------------------------------------------------------------
// Main kernel — VERIFIED BEST (R9): R2 skeleton + T5 setprio + 2x kt-unroll
// (compile-time buffer index -> LDS addresses hoisted).
// One block = one (b*h, 64-row q-tile); 2048 blocks, 4 waves.
// out = ln2*A + (1e9 - lse)*Bm - 1e9*Vsum
//   A  = sum_k mask*t*v   (t = s*log2e; Q pre-scaled by 0.125*log2e)
//   Bm = sum_k mask*v
//   lse = ln sum_k 2^t    (raw v_exp_f32 on MFMA output)
// K/V staged async via global_load_lds (pre-converted bf16, pre-swizzled),
// double-buffered with counted vmcnt(6) + raw s_barrier.
// W1 holds RAW packed scores; mask applied at PV by bitwise AND.
// SESSION LEDGER: structural variants (2-q-group R3-R7, k-stripe QK R10) all
// failed NaN/Inf in codegen-correlated ways despite conservative sync; this
// skeleton passed every run. Do not restructure without asm-level debugging.
// ---------------------------------------------------------------------------
__global__ __launch_bounds__(256, 4) void attn_kernel(
    const float* __restrict__ gq, const u16* __restrict__ wsK,
    const u16* __restrict__ wsV, const u16* __restrict__ wsM,
    const float* __restrict__ wsVs, float* __restrict__ gout) {
  __shared__ __align__(16) u16 sK[2][4096];   // 16 KB double-buffered K tile
  __shared__ __align__(16) u16 sV[2][4096];   // 16 KB double-buffered V^T tile
  __shared__ __align__(16) u16 sW1[4096];     // 8 KB: raw scores (Q staged here once)

  const int t = threadIdx.x;
  const int wv = t >> 6;
  const int lane = t & 63;
  const int c = lane & 15;
  const int quad = lane >> 4;
  const int r0 = t >> 4, c4 = t & 15;

  const int bx = blockIdx.x;
  const int bh = bx & 63;            // consecutive blocks share q0 -> mask L3 locality
  const int q0 = (bx >> 6) << 6;

  const float* qg = gq + ((size_t)bh << 17) + ((size_t)q0 << 6);
  const u16* srcK = wsK + ((size_t)bh << 17) + (t << 3);
  const u16* srcV = wsV + ((size_t)bh << 17) + (t << 3);
  const int qrow = q0 + (wv << 4) + c;
  const u16* mrow = wsM + ((size_t)qrow << 11) + (quad << 3);

  // Vsum fragments: d = 16*mt + 4*quad + j
  f32x4 vreg[4];
#pragma unroll
  for (int mt = 0; mt < 4; ++mt)
    vreg[mt] = *(const f32x4*)(wsVs + (bh << 6) + (mt << 4) + (quad << 2));

  // ---- stage Q once (scaled by 0.125*log2e) into sW1, swizzled ----
  const float qs = 0.1803368801111204f;  // 0.125 * log2(e)
#pragma unroll
  for (int i = 0; i < 4; ++i) {
    const int row = r0 + (i << 4);
    const float4 f = *(const float4*)(qg + ((size_t)row << 6) + (c4 << 2));
    const u32 lo = cvtpk(f.x * qs, f.y * qs);
    const u32 hi = cvtpk(f.z * qs, f.w * qs);
    *qkaddr(sW1, row, c4) = (u64)lo | ((u64)hi << 32);
  }
  __syncthreads();
  bf16x8 qf[2];
#pragma unroll
  for (int ks = 0; ks < 2; ++ks)
    qf[ks] = ldfrag(sW1, (wv << 4) + c, (ks << 2) + quad);
  // qf must be in regs before any wave's W1 writes (post first mid-barrier).
  asm volatile("s_waitcnt lgkmcnt(0)" ::: "memory");

  f32x4 accA[4], accB[4];
#pragma unroll
  for (int mt = 0; mt < 4; ++mt) {
    const f32x4 z = {0.f, 0.f, 0.f, 0.f};
    accA[mt] = z; accB[mt] = z;
  }
  float lacc = 0.f;

#define STAGE(kt_, buf_) do {                                        \
    const u16* sk_ = srcK + ((kt_) << 12);                           \
    const u16* sv_ = srcV + ((kt_) << 12);                           \
    u16* dk_ = &sK[buf_][wv << 9];                                   \
    u16* dv_ = &sV[buf_][wv << 9];                                   \
    gload16(sk_, dk_);                                               \
    gload16(sk_ + 2048, dk_ + 2048);                                 \
    gload16(sv_, dv_);                                               \
    gload16(sv_ + 2048, dv_ + 2048);                                 \
  } while (0)

  // One kt iteration; cur_ is a compile-time constant (0/1) so every LDS
  // address below is loop-invariant and hoists.
#define BODY(kt_, cur_) do {                                                     \
    const u16* sKc = sK[cur_];                                                   \
    const u16* sVc = sV[cur_];                                                   \
    const u32x4 mm0 = *(const u32x4*)(mrow + ((size_t)(kt_) << 6));              \
    const u32x4 mm1 = *(const u32x4*)(mrow + ((size_t)(kt_) << 6) + 32);         \
    if ((kt_) < 31) {                                                            \
      STAGE((kt_) + 1, (cur_) ^ 1);                                             \
      /* outstanding: 4 (tile kt) + 2 (mask) + 4 (tile kt+1) -> wait oldest 4 */ \
      asm volatile("s_waitcnt vmcnt(6)" ::: "memory");                           \
    } else {                                                                     \
      asm volatile("s_waitcnt vmcnt(2)" ::: "memory");                           \
    }                                                                            \
    __builtin_amdgcn_s_barrier();                                                \
    asm volatile("" ::: "memory"); /* keep tile reads below the barrier */       \
    /* QK: S^T = K*Q^T (t-units), exp2 accumulation, raw-score W1 */             \
    _Pragma("unroll")                                                            \
    for (int tr = 0; tr < 4; ++tr) {                                             \
      f32x4 acc = {0.f, 0.f, 0.f, 0.f};                                          \
      __builtin_amdgcn_s_setprio(1);                                             \
      acc = MFMA16(ldfrag(sKc, (tr << 4) + c, quad), qf[0], acc, 0, 0, 0);       \
      acc = MFMA16(ldfrag(sKc, (tr << 4) + c, 4 + quad), qf[1], acc, 0, 0, 0);   \
      __builtin_amdgcn_s_setprio(0);                                             \
      lacc += (exp2hw(acc[0]) + exp2hw(acc[1])) +                                \
              (exp2hw(acc[2]) + exp2hw(acc[3]));                                 \
      *qkaddr(sW1, (wv << 4) + c, (tr << 2) + quad) =                            \
          (u64)cvtpk(acc[0], acc[1]) | ((u64)cvtpk(acc[2], acc[3]) << 32);       \
    }                                                                            \
    /* PV: mask applied by AND; W wave-private -> no barrier needed */           \
    _Pragma("unroll")                                                            \
    for (int ks = 0; ks < 2; ++ks) {                                             \
      const u32x4 m = ks ? mm1 : mm0;                                            \
      const bf16x8 wr = ldfrag(sW1, (wv << 4) + c, (ks << 2) + quad);            \
      const u32x4 wraw = __builtin_bit_cast(u32x4, wr);                          \
      const bf16x8 bw1 = __builtin_bit_cast(bf16x8, wraw & m);                   \
      const bf16x8 bw2 = __builtin_bit_cast(bf16x8, m & 0x3F803F80u);            \
      __builtin_amdgcn_s_setprio(1);                                             \
      _Pragma("unroll")                                                          \
      for (int mt = 0; mt < 4; ++mt) {                                           \
        const bf16x8 av = ldfrag(sVc, (mt << 4) + c, (ks << 2) + quad);          \
        accA[mt] = MFMA16(av, bw1, accA[mt], 0, 0, 0);                           \
        accB[mt] = MFMA16(av, bw2, accB[mt], 0, 0, 0);                           \
      }                                                                          \
      __builtin_amdgcn_s_setprio(0);                                             \
    }                                                                            \
    /* drain this wave's LDS reads before buf[cur] is overwritten (kt+2) */      \
    asm volatile("s_waitcnt lgkmcnt(0)" ::: "memory");                           \
    __builtin_amdgcn_s_barrier();                                                \
  } while (0)

  STAGE(0, 0);

  for (int kt = 0; kt < 32; kt += 2) {
    BODY(kt, 0);
    BODY(kt + 1, 1);
  }
#undef STAGE
#undef BODY

  // ---- lse (wave-local: quad butterflies only) ----
  float l = lacc;
  l += __shfl_xor(l, 16, 64);
  l += __shfl_xor(l, 32, 64);
  l = __log2f(l) * 0.6931471805599453f;
  const float c1 = 1e9f - l;

  // ---- epilogue: out[b][q][h*64+d] = ln2*A + c1*Bm - 1e9*Vsum ----
  const int b = bh >> 4, h = bh & 15;
  const float ln2 = 0.6931471805599453f;
#pragma unroll
  for (int mt = 0; mt < 4; ++mt) {
    float4 o;
    o.x = ln2 * accA[mt][0] + c1 * accB[mt][0] - 1e9f * vreg[mt][0];
    o.y = ln2 * accA[mt][1] + c1 * accB[mt][1] - 1e9f * vreg[mt][1];
    o.z = ln2 * accA[mt][2] + c1 * accB[mt][2] - 1e9f * vreg[mt][2];
    o.w = ln2 * accA[mt][3] + c1 * accB[mt][3] - 1e9f * vreg[mt][3];
    const size_t off = ((size_t)b * S_LEN + (size_t)qrow) * 1024 +
                       (h << 6) + (mt << 4) + (quad << 2);
    *(float4*)(gout + off) = o;
  }
}

extern "C" void kernel_launch(void* const* d_in, const int* in_sizes, int n_in,
                              void* d_out, int out_size, void* d_ws, size_t ws_size,
                              hipStream_t stream) {
  const float* q = (const float*)d_in[0];
  const float* k = (const float*)d_in[1];
  const float* v = (const float*)d_in[2];
  const int* mask = (const int*)d_in[3];
  (void)in_sizes; (void)n_in; (void)out_size; (void)ws_size;
  // workspace: wsK 16MB | wsV 16MB | wsM 8MB | wsVs 16KB  (~42MB total)
  u16* wsK = (u16*)d_ws;
  u16* wsV = wsK + ((size_t)64 << 17);
  u16* wsM = wsV + ((size_t)64 << 17);
  float* wsVs = (float*)(wsM + ((size_t)S_LEN * S_LEN));
  hipMemsetAsync(wsVs, 0, 64 * 64 * sizeof(float), stream);
  prep_kernel<<<dim3(3072), dim3(256), 0, stream>>>(k, v, mask, wsK, wsV, wsM, wsVs);
  attn_kernel<<<dim3(2048), dim3(256), 0, stream>>>(q, wsK, wsV, wsM, wsVs, (float*)d_out);
}

// Round 12
// 284.975 us; speedup vs baseline: 1.0225x; 1.0225x over previous
//
#include <hip/hip_runtime.h>

#define S_LEN 2048

typedef __attribute__((ext_vector_type(8))) short bf16x8;
typedef __attribute__((ext_vector_type(4))) float f32x4;
typedef __attribute__((ext_vector_type(4))) unsigned int u32x4;
typedef unsigned long long u64;
typedef unsigned int u32;
typedef unsigned short u16;

#define MFMA16 __builtin_amdgcn_mfma_f32_16x16x32_bf16

// single-instruction pack: a -> low16, b -> high16 (RNE)
__device__ __forceinline__ u32 cvtpk(float a, float b) {
  u32 r;
  asm("v_cvt_pk_bf16_f32 %0, %1, %2" : "=v"(r) : "v"(a), "v"(b));
  return r;
}
// raw hardware 2^x (avoid OCML wrapper ops around v_exp_f32)
__device__ __forceinline__ float exp2hw(float x) {
  float r;
  asm("v_exp_f32 %0, %1" : "=v"(r) : "v"(x));
  return r;
}

// 128B-row tile, 8 x 16B blocks/row, block swizzled by xor(row&7). (K, Q, W)
__device__ __forceinline__ u64* qkaddr(u16* dst, int row, int c4) {
  const int cb = c4 >> 1;
  return (u64*)((char*)dst + ((((row << 3) + (cb ^ (row & 7))) << 4) + ((c4 & 1) << 3)));
}
__device__ __forceinline__ bf16x8 ldfrag(const u16* base, int row, int blk) {
  const char* p = (const char*)base + (((row << 3) + (blk ^ (row & 7))) << 4);
  return *(const bf16x8*)p;
}
// 64B-row tile (V^T 32-k sub-tiles): 4 x 16B blocks/row, swizzled by xor(row&3).
__device__ __forceinline__ bf16x8 ldv32(const u16* base, int row, int blk) {
  const char* p = (const char*)base + (((row << 2) + (blk ^ (row & 3))) << 4);
  return *(const bf16x8*)p;
}

// async global->LDS, 16B per lane; LDS dst = wave-uniform base + lane*16.
__device__ __forceinline__ void gload16(const u16* g, u16* l) {
  __builtin_amdgcn_global_load_lds((const __attribute__((address_space(1))) void*)g,
                                   (__attribute__((address_space(3))) void*)l, 16, 0, 0);
}

// ---------------------------------------------------------------------------
// Pre-pass. K/mask sections unchanged (K 32-k sub-tiles are already contiguous
// rows 0..31 / 32..63 of the existing layout). V^T now emitted as TWO 32-k
// sub-tiles per (bh,kt64): 64 d-rows x 32 k, 64B rows, physical block
// pb = cb ^ (d&3) (matches ldv32). Stores remain fully coalesced (addr=t<<3).
// ---------------------------------------------------------------------------
__global__ __launch_bounds__(256) void prep_kernel(
    const float* __restrict__ gk, const float* __restrict__ gv,
    const int* __restrict__ gmask,
    u16* __restrict__ wsK, u16* __restrict__ wsV,
    u16* __restrict__ wsM, float* __restrict__ wsVs) {
  __shared__ float tile[64 * 65];   // V^T staged: tile[d*65 + k] (65-stride: bank-free)
  __shared__ float sred[2][256];    // Vsum partials
  const int bid = blockIdx.x, t = threadIdx.x;
  if (bid < 2048) {
    const int bh = bid >> 5, kt = bid & 31;
    const float* kg = gk + ((size_t)bh << 17) + ((size_t)kt << 12);
    const float* vg = gv + ((size_t)bh << 17) + ((size_t)kt << 12);
    u16* outK = wsK + ((size_t)bid << 12);
    u16* outV = wsV + ((size_t)bid << 12);
    const int r0 = t >> 4, c4 = t & 15;
#pragma unroll
    for (int i = 0; i < 4; ++i) {
      const int row = r0 + (i << 4);  // k index
      const float4 f = *(const float4*)(vg + (row << 6) + (c4 << 2));
      float* p = tile + row;
      p[((c4 << 2) + 0) * 65] = f.x;
      p[((c4 << 2) + 1) * 65] = f.y;
      p[((c4 << 2) + 2) * 65] = f.z;
      p[((c4 << 2) + 3) * 65] = f.w;
    }
#pragma unroll
    for (int i = 0; i < 2; ++i) {
      const int n = t + (i << 8);
      const int row = n >> 3, cb = (n & 7) ^ (row & 7);
      const float4 A = *(const float4*)(kg + (row << 6) + (cb << 3));
      const float4 B = *(const float4*)(kg + (row << 6) + (cb << 3) + 4);
      u32x4 w;
      w.x = cvtpk(A.x, A.y); w.y = cvtpk(A.z, A.w);
      w.z = cvtpk(B.x, B.y); w.w = cvtpk(B.z, B.w);
      *(u32x4*)(outK + ((size_t)n << 3)) = w;
    }
    __syncthreads();
    // ---- V^T: two 32-k sub-tiles; d = t>>2, physical block pb = t&3 ----
#pragma unroll
    for (int i = 0; i < 2; ++i) {
      const int d = t >> 2, pb = t & 3;
      const int cb = pb ^ (d & 3);                 // logical k-block stored here
      const float* src = tile + d * 65 + (i << 5) + (cb << 3);
      float e[8], s = 0.f;
#pragma unroll
      for (int j = 0; j < 8; ++j) { e[j] = src[j]; s += e[j]; }
      sred[i][t] = s;
      u32x4 w;
      w.x = cvtpk(e[0], e[1]); w.y = cvtpk(e[2], e[3]);
      w.z = cvtpk(e[4], e[5]); w.w = cvtpk(e[6], e[7]);
      *(u32x4*)(outV + ((size_t)i << 11) + ((size_t)t << 3)) = w;
    }
    __syncthreads();
    if (t < 64) {
      // Vsum[d=t]: partials at threads 4t..4t+3, both sub-tiles
      float s = 0.f;
#pragma unroll
      for (int i = 0; i < 2; ++i)
#pragma unroll
        for (int u = 0; u < 4; ++u) s += sred[i][(t << 2) + u];
      atomicAdd(&wsVs[(bh << 6) + t], s);
    }
  } else {
    const size_t base = ((size_t)(bid - 2048) << 12) + ((size_t)t << 4);
    int4 m[4];
#pragma unroll
    for (int i = 0; i < 4; ++i) m[i] = *(const int4*)(gmask + base + (i << 2));
    u32x4 w0, w1;
    w0.x = (m[0].x ? 0xFFFFu : 0u) | (m[0].y ? 0xFFFF0000u : 0u);
    w0.y = (m[0].z ? 0xFFFFu : 0u) | (m[0].w ? 0xFFFF0000u : 0u);
    w0.z = (m[1].x ? 0xFFFFu : 0u) | (m[1].y ? 0xFFFF0000u : 0u);
    w0.w = (m[1].z ? 0xFFFFu : 0u) | (m[1].w ? 0xFFFF0000u : 0u);
    w1.x = (m[2].x ? 0xFFFFu : 0u) | (m[2].y ? 0xFFFF0000u : 0u);
    w1.y = (m[2].z ? 0xFFFFu : 0u) | (m[2].w ? 0xFFFF0000u : 0u);
    w1.z = (m[3].x ? 0xFFFFu : 0u) | (m[3].y ? 0xFFFF0000u : 0u);
    w1.w = (m[3].z ? 0xFFFFu : 0u) | (m[3].w ? 0xFFFF0000u : 0u);
    *(u32x4*)(wsM + base) = w0;
    *(u32x4*)(wsM + base + 8) = w1;
  }
}

// ---------------------------------------------------------------------------
// Main kernel — R9 dataflow, k-tile 64 -> 32 (parameter change only).
// LDS 40 -> 24 KB => 6 blocks/CU (24 waves, 75% occupancy) vs 3 (39%).
// Same sync skeleton: STAGE(kt+1) before barrier1 (counted vmcnt(3)),
// QK -> same-wave W1 round-trip -> PV, lgkm drain + barrier2. 64 iterations.
// out = ln2*A + (1e9 - lse)*Bm - 1e9*Vsum   (unchanged algebra)
// SESSION LEDGER: dataflow changes (2-q-group R3-R7, k-stripe R10) all failed;
// parameter changes (unroll R9, this) keep the proven wave roles/swizzles.
// ---------------------------------------------------------------------------
__global__ __launch_bounds__(256, 4) void attn_kernel(
    const float* __restrict__ gq, const u16* __restrict__ wsK,
    const u16* __restrict__ wsV, const u16* __restrict__ wsM,
    const float* __restrict__ wsVs, float* __restrict__ gout) {
  __shared__ __align__(16) u16 sK[2][2048];   // 8 KB double-buffered K tile (32k x 64d)
  __shared__ __align__(16) u16 sV[2][2048];   // 8 KB double-buffered V^T tile (64d x 32k)
  __shared__ __align__(16) u16 sW1[4096];     // 8 KB: raw scores (Q staged here once)

  const int t = threadIdx.x;
  const int wv = t >> 6;
  const int lane = t & 63;
  const int c = lane & 15;
  const int quad = lane >> 4;
  const int r0 = t >> 4, c4 = t & 15;

  const int bx = blockIdx.x;
  const int bh = bx & 63;            // consecutive blocks share q0 -> mask L3 locality
  const int q0 = (bx >> 6) << 6;

  const float* qg = gq + ((size_t)bh << 17) + ((size_t)q0 << 6);
  const u16* srcK = wsK + ((size_t)bh << 17) + (t << 3);
  const u16* srcV = wsV + ((size_t)bh << 17) + (t << 3);
  const int qrow = q0 + (wv << 4) + c;
  const u16* mrow = wsM + ((size_t)qrow << 11) + (quad << 3);

  // Vsum fragments: d = 16*mt + 4*quad + j
  f32x4 vreg[4];
#pragma unroll
  for (int mt = 0; mt < 4; ++mt)
    vreg[mt] = *(const f32x4*)(wsVs + (bh << 6) + (mt << 4) + (quad << 2));

  // ---- stage Q once (scaled by 0.125*log2e) into sW1, swizzled ----
  const float qs = 0.1803368801111204f;  // 0.125 * log2(e)
#pragma unroll
  for (int i = 0; i < 4; ++i) {
    const int row = r0 + (i << 4);
    const float4 f = *(const float4*)(qg + ((size_t)row << 6) + (c4 << 2));
    const u32 lo = cvtpk(f.x * qs, f.y * qs);
    const u32 hi = cvtpk(f.z * qs, f.w * qs);
    *qkaddr(sW1, row, c4) = (u64)lo | ((u64)hi << 32);
  }
  __syncthreads();
  bf16x8 qf[2];
#pragma unroll
  for (int ks = 0; ks < 2; ++ks)
    qf[ks] = ldfrag(sW1, (wv << 4) + c, (ks << 2) + quad);
  // qf must be in regs before any wave's W1 writes (post first mid-barrier).
  asm volatile("s_waitcnt lgkmcnt(0)" ::: "memory");

  f32x4 accA[4], accB[4];
#pragma unroll
  for (int mt = 0; mt < 4; ++mt) {
    const f32x4 z = {0.f, 0.f, 0.f, 0.f};
    accA[mt] = z; accB[mt] = z;
  }
  float lacc = 0.f;

  // 32-k sub-tile: 4 KB each for K and V^T -> 1 gload16 per wave per tensor.
#define STAGE(kt_, buf_) do {                                        \
    const u16* sk_ = srcK + ((size_t)(kt_) << 11);                   \
    const u16* sv_ = srcV + ((size_t)(kt_) << 11);                   \
    gload16(sk_, &sK[buf_][wv << 9]);                                \
    gload16(sv_, &sV[buf_][wv << 9]);                                \
  } while (0)

  // One 32-k iteration; cur_ compile-time (R9 unroll win kept).
#define BODY(kt_, cur_) do {                                                     \
    const u16* sKc = sK[cur_];                                                   \
    const u16* sVc = sV[cur_];                                                   \
    const u32x4 mm = *(const u32x4*)(mrow + ((size_t)(kt_) << 5));               \
    if ((kt_) < 63) {                                                            \
      STAGE((kt_) + 1, (cur_) ^ 1);                                             \
      /* outstanding: 2 (tile kt) + 1 (mask) + 2 (tile kt+1) -> wait oldest 2 */ \
      asm volatile("s_waitcnt vmcnt(3)" ::: "memory");                           \
    } else {                                                                     \
      asm volatile("s_waitcnt vmcnt(1)" ::: "memory");                           \
    }                                                                            \
    __builtin_amdgcn_s_barrier();                                                \
    asm volatile("" ::: "memory"); /* keep tile reads below the barrier */       \
    /* QK: S^T = K*Q^T (t-units), exp2 accumulation, raw-score W1 */             \
    _Pragma("unroll")                                                            \
    for (int tr = 0; tr < 2; ++tr) {                                             \
      f32x4 acc = {0.f, 0.f, 0.f, 0.f};                                          \
      __builtin_amdgcn_s_setprio(1);                                             \
      acc = MFMA16(ldfrag(sKc, (tr << 4) + c, quad), qf[0], acc, 0, 0, 0);       \
      acc = MFMA16(ldfrag(sKc, (tr << 4) + c, 4 + quad), qf[1], acc, 0, 0, 0);   \
      __builtin_amdgcn_s_setprio(0);                                             \
      lacc += (exp2hw(acc[0]) + exp2hw(acc[1])) +                                \
              (exp2hw(acc[2]) + exp2hw(acc[3]));                                 \
      *qkaddr(sW1, (wv << 4) + c, (tr << 2) + quad) =                            \
          (u64)cvtpk(acc[0], acc[1]) | ((u64)cvtpk(acc[2], acc[3]) << 32);       \
    }                                                                            \
    /* PV: single 32-wide k-half; mask applied by AND; W wave-private */         \
    {                                                                            \
      const bf16x8 wr = ldfrag(sW1, (wv << 4) + c, quad);                        \
      const u32x4 wraw = __builtin_bit_cast(u32x4, wr);                          \
      const bf16x8 bw1 = __builtin_bit_cast(bf16x8, wraw & mm);                  \
      const bf16x8 bw2 = __builtin_bit_cast(bf16x8, mm & 0x3F803F80u);           \
      __builtin_amdgcn_s_setprio(1);                                             \
      _Pragma("unroll")                                                          \
      for (int mt = 0; mt < 4; ++mt) {                                           \
        const bf16x8 av = ldv32(sVc, (mt << 4) + c, quad);                       \
        accA[mt] = MFMA16(av, bw1, accA[mt], 0, 0, 0);                           \
        accB[mt] = MFMA16(av, bw2, accB[mt], 0, 0, 0);                           \
      }                                                                          \
      __builtin_amdgcn_s_setprio(0);                                             \
    }                                                                            \
    /* drain this wave's LDS reads before buf[cur] is overwritten (kt+2) */      \
    asm volatile("s_waitcnt lgkmcnt(0)" ::: "memory");                           \
    __builtin_amdgcn_s_barrier();                                                \
  } while (0)

  STAGE(0, 0);

  for (int kt = 0; kt < 64; kt += 2) {
    BODY(kt, 0);
    BODY(kt + 1, 1);
  }
#undef STAGE
#undef BODY

  // ---- lse (wave-local: quad butterflies only) ----
  float l = lacc;
  l += __shfl_xor(l, 16, 64);
  l += __shfl_xor(l, 32, 64);
  l = __log2f(l) * 0.6931471805599453f;
  const float c1 = 1e9f - l;

  // ---- epilogue: out[b][q][h*64+d] = ln2*A + c1*Bm - 1e9*Vsum ----
  const int b = bh >> 4, h = bh & 15;
  const float ln2 = 0.6931471805599453f;
#pragma unroll
  for (int mt = 0; mt < 4; ++mt) {
    float4 o;
    o.x = ln2 * accA[mt][0] + c1 * accB[mt][0] - 1e9f * vreg[mt][0];
    o.y = ln2 * accA[mt][1] + c1 * accB[mt][1] - 1e9f * vreg[mt][1];
    o.z = ln2 * accA[mt][2] + c1 * accB[mt][2] - 1e9f * vreg[mt][2];
    o.w = ln2 * accA[mt][3] + c1 * accB[mt][3] - 1e9f * vreg[mt][3];
    const size_t off = ((size_t)b * S_LEN + (size_t)qrow) * 1024 +
                       (h << 6) + (mt << 4) + (quad << 2);
    *(float4*)(gout + off) = o;
  }
}

extern "C" void kernel_launch(void* const* d_in, const int* in_sizes, int n_in,
                              void* d_out, int out_size, void* d_ws, size_t ws_size,
                              hipStream_t stream) {
  const float* q = (const float*)d_in[0];
  const float* k = (const float*)d_in[1];
  const float* v = (const float*)d_in[2];
  const int* mask = (const int*)d_in[3];
  (void)in_sizes; (void)n_in; (void)out_size; (void)ws_size;
  // workspace: wsK 16MB | wsV 16MB | wsM 8MB | wsVs 16KB  (~42MB total)
  u16* wsK = (u16*)d_ws;
  u16* wsV = wsK + ((size_t)64 << 17);
  u16* wsM = wsV + ((size_t)64 << 17);
  float* wsVs = (float*)(wsM + ((size_t)S_LEN * S_LEN));
  hipMemsetAsync(wsVs, 0, 64 * 64 * sizeof(float), stream);
  prep_kernel<<<dim3(3072), dim3(256), 0, stream>>>(k, v, mask, wsK, wsV, wsM, wsVs);
  attn_kernel<<<dim3(2048), dim3(256), 0, stream>>>(q, wsK, wsV, wsM, wsVs, (float*)d_out);
}